// Round 3
// baseline (136.785 us; speedup 1.0000x reference)
//
#include <hip/hip_runtime.h>

// ---------------------------------------------------------------------------
// HR2HK: build k-space Hamiltonian H[k, N*13, N*13] from real-space edge/node
// features, with Hermitian symmetrization (H + conj(H^T)) folded in:
//   - diagonal blocks: 0.5*(O[r,c]+O[c,r])  (real)
//   - per edge (src,dst): block += hop*e^{-i theta}, mirror += hop^T*e^{+i theta}
//
// DUAL MODE keyed off out_size (defensive vs harness complex64 handling):
//   out_size == 2*K*DIM*DIM : interleaved complex64 (re,im float pairs)
//   otherwise               : real-part-only float32 layout [K, DIM, DIM]
// ALL writes bounds-guarded by out_lim (floats) -> cannot fault.
// ---------------------------------------------------------------------------

// orbital structure: l = [0,0,1,1,2], sizes {1,1,3,3,5}, offsets {0,1,2,5,8}
__device__ __forceinline__ void orb_of(int r, int& i, int& ri, int& nv) {
    if (r < 1)      { i = 0; ri = r;     nv = 1; }
    else if (r < 2) { i = 1; ri = r - 1; nv = 1; }
    else if (r < 5) { i = 2; ri = r - 2; nv = 3; }
    else if (r < 8) { i = 3; ri = r - 5; nv = 3; }
    else            { i = 4; ri = r - 8; nv = 5; }
}
__device__ __forceinline__ int offs_of(int i) {
    return i == 0 ? 0 : (i == 1 ? 1 : (i == 2 ? 2 : (i == 3 ? 5 : 8)));
}
// rowstart[i] = sum_{i'<i} nv[i'] * (13 - offs[i'])  -> {0,13,25,58,82}
__device__ __forceinline__ int rowstart_of(int i) {
    return i == 0 ? 0 : (i == 1 ? 13 : (i == 2 ? 25 : (i == 3 ? 58 : 82)));
}
// P[r,c]: index into 169-long edge feature vector (row-major over all pairs)
__device__ __forceinline__ int pmap(int r, int c) {
    int i, ri, nvi, j, cj, nvj;
    orb_of(r, i, ri, nvi);
    orb_of(c, j, cj, nvj);
    return 13 * offs_of(i) + nvi * offs_of(j) + ri * nvj + cj;
}
// Nm[r,c]: index into 107-long node feature vector (upper blocks; transposed read)
__device__ __forceinline__ int nmap(int r, int c) {
    int i, ri, nvi, j, cj, nvj;
    orb_of(r, i, ri, nvi);
    orb_of(c, j, cj, nvj);
    if (i <= j)
        return rowstart_of(i) + nvi * (offs_of(j) - offs_of(i)) + ri * nvj + cj;
    else
        return rowstart_of(j) + nvj * (offs_of(i) - offs_of(j)) + cj * nvi + ri;
}

// ---------------------------------------------------------------------------
// Kernel 1: zero out_size floats (float4 main + scalar tail), grid-stride.
// ---------------------------------------------------------------------------
__global__ __launch_bounds__(256) void zero_kernel(float* __restrict__ out, long n) {
    long n4 = n >> 2;
    float4* out4 = (float4*)out;
    long i = (long)blockIdx.x * blockDim.x + threadIdx.x;
    long stride = (long)gridDim.x * blockDim.x;
    const float4 z = {0.f, 0.f, 0.f, 0.f};
    for (long t = i; t < n4; t += stride) out4[t] = z;
    if (i == 0) for (long j = n4 << 2; j < n; ++j) out[j] = 0.f;
}

// ---------------------------------------------------------------------------
// Kernel 2: diagonal onsite blocks (plain stores after zero-fill).
// ---------------------------------------------------------------------------
template <int CPLX>
__global__ __launch_bounds__(256) void diag_kernel(const float* __restrict__ nf,
                                                   float* __restrict__ out,
                                                   int N, int total, long out_lim) {
    int t = blockIdx.x * blockDim.x + threadIdx.x;
    if (t >= total) return;
    int per_k = N * 169;
    int k   = t / per_k;
    int rem = t - k * per_k;
    int n   = rem / 169;
    int idx = rem - n * 169;
    int r = idx / 13, c = idx - r * 13;
    float v = 0.5f * (nf[n * 107 + nmap(r, c)] + nf[n * 107 + nmap(c, r)]);
    long DIM = (long)N * 13;
    long off = ((long)k * DIM + (long)n * 13 + r) * DIM + (long)n * 13 + c;
    if (CPLX) off *= 2;                      // real slot; imag stays 0
    if (off >= 0 && off < out_lim) out[off] = v;
}

// ---------------------------------------------------------------------------
// Kernel 3: one block per edge. hop block staged P-permuted in LDS; K phases
// in LDS; each active thread owns (r,c), writes its H0 entry and the mirror
// of its TRANSPOSED entry so both streams coalesce in 13-float runs.
// ---------------------------------------------------------------------------
template <int CPLX>
__global__ __launch_bounds__(256) void edge_kernel(const float* __restrict__ ef,
                                                   const float* __restrict__ kp,
                                                   const float* __restrict__ ecs,
                                                   const int*   __restrict__ eidx,
                                                   float* __restrict__ out,
                                                   int N, int E, int K, long out_lim) {
    const int e = blockIdx.x;
    __shared__ float hop_sh[169];
    __shared__ float cos_sh[32];
    __shared__ float sin_sh[32];
    const int tid = threadIdx.x;
    const int r = tid / 13, c = tid - r * 13;   // valid when tid < 169

    if (tid < 169) {
        hop_sh[tid] = ef[(long)e * 169 + pmap(r, c)];
    }
    if (tid < K && tid < 32) {
        float sx = ecs[e * 3 + 0], sy = ecs[e * 3 + 1], sz = ecs[e * 3 + 2];
        float dot = kp[tid * 3 + 0] * sx + kp[tid * 3 + 1] * sy + kp[tid * 3 + 2] * sz;
        float th = 6.28318530717958647692f * dot;
        float s, co;
        sincosf(th, &s, &co);                    // phase = cos(th) - i*sin(th)
        cos_sh[tid] = co;
        sin_sh[tid] = s;
    }
    __syncthreads();
    if (tid >= 169) return;

    const int src = eidx[e];
    const int dst = eidx[E + e];
    const long DIM = (long)N * 13;
    const long SL  = DIM * DIM;

    const float h  = hop_sh[tid];                // hop[r][c]
    const float ht = hop_sh[c * 13 + r];         // hop[c][r]
    // H0 entry (r,c):      row = src*13+r, col = dst*13+c   -> h * e^{-i th}
    // mirror of (c,r):     row = dst*13+r, col = src*13+c   -> ht * e^{+i th}
    const long base1 = ((long)src * 13 + r) * DIM + (long)dst * 13 + c;
    const long base2 = ((long)dst * 13 + r) * DIM + (long)src * 13 + c;

    for (int k = 0; k < K; ++k) {
        float co = cos_sh[k & 31];
        float si = sin_sh[k & 31];
        if (CPLX) {
            long o1 = ((long)k * SL + base1) * 2;
            long o2 = ((long)k * SL + base2) * 2;
            if (o1 >= 0 && o1 + 1 < out_lim) {
                atomicAdd(out + o1,     h * co);
                atomicAdd(out + o1 + 1, -h * si);
            }
            if (o2 >= 0 && o2 + 1 < out_lim) {
                atomicAdd(out + o2,     ht * co);
                atomicAdd(out + o2 + 1, ht * si);
            }
        } else {
            long o1 = (long)k * SL + base1;
            long o2 = (long)k * SL + base2;
            if (o1 >= 0 && o1 < out_lim) atomicAdd(out + o1, h * co);
            if (o2 >= 0 && o2 < out_lim) atomicAdd(out + o2, ht * co);
        }
    }
}

extern "C" void kernel_launch(void* const* d_in, const int* in_sizes, int n_in,
                              void* d_out, int out_size, void* d_ws, size_t ws_size,
                              hipStream_t stream) {
    const float* ef   = (const float*)d_in[0];   // edge_features   (E, 169)
    const float* nf   = (const float*)d_in[1];   // node_features   (N, 107)
    const float* kp   = (const float*)d_in[2];   // kpoints         (K, 3)
    const float* ecs  = (const float*)d_in[3];   // edge_cell_shift (E, 3)
    const int*   eidx = (const int*)d_in[4];     // edge_index      (2, E)

    const int E = in_sizes[0] / 169;
    const int N = in_sizes[1] / 107;
    const int K = in_sizes[2] / 3;

    float* out = (float*)d_out;
    const long DIM  = (long)N * 13;
    const long SL   = DIM * DIM;
    const long full = (long)K * SL * 2;          // floats if interleaved complex
    const int  cplx = ((long)out_size >= full) ? 1 : 0;
    const long out_lim = (long)out_size;         // hard clamp for every write

    // 1) zero-fill exactly out_size floats
    zero_kernel<<<2048, 256, 0, stream>>>(out, out_lim);

    // 2) diagonal onsite blocks
    int total_diag = K * N * 169;
    int blocks_diag = (total_diag + 255) / 256;
    if (cplx)
        diag_kernel<1><<<blocks_diag, 256, 0, stream>>>(nf, out, N, total_diag, out_lim);
    else
        diag_kernel<0><<<blocks_diag, 256, 0, stream>>>(nf, out, N, total_diag, out_lim);

    // 3) edge scatter with Hermitian mirror
    if (cplx)
        edge_kernel<1><<<E, 256, 0, stream>>>(ef, kp, ecs, eidx, out, N, E, K, out_lim);
    else
        edge_kernel<0><<<E, 256, 0, stream>>>(ef, kp, ecs, eidx, out, N, E, K, out_lim);
}

// Round 4
// 121.541 us; speedup vs baseline: 1.1254x; 1.1254x over previous
//
#include <hip/hip_runtime.h>

// ---------------------------------------------------------------------------
// HR2HK: H[k, N*13, N*13] from edge/node features, Hermitian fold-in.
// Output-driven single pass over H: one workgroup per output row builds the
// row in LDS (diag + incident-edge segments via LDS atomics) and streams it
// out with coalesced float4 stores — every output byte written exactly once.
// Preprocessing (tiny, in d_ws): P-permuted hop/hopT per edge, per-(e,k)
// phases, symmetrized onsite blocks, CSR adjacency by src and by dst.
// Dual-mode layout keyed off out_size (proven in round 3):
//   out_size >= 2*K*DIM^2 : interleaved complex64 (re,im)
//   else                  : real-part-only float32
// Fallback to the verified round-3 3-kernel path if ws/shape limits exceeded.
// ---------------------------------------------------------------------------

// orbital structure: l = [0,0,1,1,2], sizes {1,1,3,3,5}, offsets {0,1,2,5,8}
__device__ __forceinline__ void orb_of(int r, int& i, int& ri, int& nv) {
    if (r < 1)      { i = 0; ri = r;     nv = 1; }
    else if (r < 2) { i = 1; ri = r - 1; nv = 1; }
    else if (r < 5) { i = 2; ri = r - 2; nv = 3; }
    else if (r < 8) { i = 3; ri = r - 5; nv = 3; }
    else            { i = 4; ri = r - 8; nv = 5; }
}
__device__ __forceinline__ int offs_of(int i) {
    return i == 0 ? 0 : (i == 1 ? 1 : (i == 2 ? 2 : (i == 3 ? 5 : 8)));
}
__device__ __forceinline__ int rowstart_of(int i) {   // {0,13,25,58,82}
    return i == 0 ? 0 : (i == 1 ? 13 : (i == 2 ? 25 : (i == 3 ? 58 : 82)));
}
__device__ __forceinline__ int pmap(int r, int c) {
    int i, ri, nvi, j, cj, nvj;
    orb_of(r, i, ri, nvi);
    orb_of(c, j, cj, nvj);
    return 13 * offs_of(i) + nvi * offs_of(j) + ri * nvj + cj;
}
__device__ __forceinline__ int nmap(int r, int c) {
    int i, ri, nvi, j, cj, nvj;
    orb_of(r, i, ri, nvi);
    orb_of(c, j, cj, nvj);
    if (i <= j)
        return rowstart_of(i) + nvi * (offs_of(j) - offs_of(i)) + ri * nvj + cj;
    else
        return rowstart_of(j) + nvj * (offs_of(i) - offs_of(j)) + cj * nvi + ri;
}

// ============================ preprocessing ================================

__global__ __launch_bounds__(256) void zero_ints_kernel(int* __restrict__ p, int n) {
    int i = blockIdx.x * blockDim.x + threadIdx.x;
    if (i < n) p[i] = 0;
}

// per-edge: permute hop & hopT, compute K phases, count degrees
__global__ __launch_bounds__(256) void edge_pre_kernel(const float* __restrict__ ef,
                                                       const float* __restrict__ kp,
                                                       const float* __restrict__ ecs,
                                                       const int*   __restrict__ eidx,
                                                       float* __restrict__ phases,
                                                       float* __restrict__ hop_pre,
                                                       float* __restrict__ hopT_pre,
                                                       int* __restrict__ cnt_src,
                                                       int* __restrict__ cnt_dst,
                                                       int E, int K) {
    const int e = blockIdx.x;
    const int tid = threadIdx.x;
    if (tid < 169) {
        int r = tid / 13, c = tid - r * 13;
        hop_pre [(long)e * 169 + tid] = ef[(long)e * 169 + pmap(r, c)];
        hopT_pre[(long)e * 169 + tid] = ef[(long)e * 169 + pmap(c, r)];
    }
    if (tid < K) {
        float sx = ecs[e * 3 + 0], sy = ecs[e * 3 + 1], sz = ecs[e * 3 + 2];
        float dot = kp[tid * 3 + 0] * sx + kp[tid * 3 + 1] * sy + kp[tid * 3 + 2] * sz;
        float th = 6.28318530717958647692f * dot;
        float s, co;
        sincosf(th, &s, &co);
        phases[((long)e * K + tid) * 2 + 0] = co;
        phases[((long)e * K + tid) * 2 + 1] = s;
    }
    if (tid == 0) {
        atomicAdd(&cnt_src[eidx[e]], 1);
        atomicAdd(&cnt_dst[eidx[E + e]], 1);
    }
}

// symmetrized onsite blocks: onsite[n][r*13+c] = 0.5*(O[r,c]+O[c,r])
__global__ __launch_bounds__(256) void onsite_pre_kernel(const float* __restrict__ nf,
                                                         float* __restrict__ onsite,
                                                         int total) {
    int t = blockIdx.x * blockDim.x + threadIdx.x;
    if (t >= total) return;
    int n = t / 169, idx = t - n * 169;
    int r = idx / 13, c = idx - r * 13;
    onsite[t] = 0.5f * (nf[n * 107 + nmap(r, c)] + nf[n * 107 + nmap(c, r)]);
}

// exclusive scan of both degree arrays (N <= 256), one block of 256
__global__ __launch_bounds__(256) void scan_kernel(const int* __restrict__ cnt_src,
                                                   const int* __restrict__ cnt_dst,
                                                   int* __restrict__ off_src,
                                                   int* __restrict__ off_dst,
                                                   int* __restrict__ woff_src,
                                                   int* __restrict__ woff_dst,
                                                   int N) {
    __shared__ int sh[256];
    const int tid = threadIdx.x;

    int v = (tid < N) ? cnt_src[tid] : 0;
    sh[tid] = v; __syncthreads();
    for (int o = 1; o < 256; o <<= 1) {
        int t = (tid >= o) ? sh[tid - o] : 0;
        __syncthreads();
        sh[tid] += t;
        __syncthreads();
    }
    if (tid < N) { int ex = sh[tid] - v; off_src[tid] = ex; woff_src[tid] = ex; }
    if (tid == 0) off_src[N] = sh[255];
    __syncthreads();

    int v2 = (tid < N) ? cnt_dst[tid] : 0;
    sh[tid] = v2; __syncthreads();
    for (int o = 1; o < 256; o <<= 1) {
        int t = (tid >= o) ? sh[tid - o] : 0;
        __syncthreads();
        sh[tid] += t;
        __syncthreads();
    }
    if (tid < N) { int ex = sh[tid] - v2; off_dst[tid] = ex; woff_dst[tid] = ex; }
    if (tid == 0) off_dst[N] = sh[255];
}

__global__ __launch_bounds__(256) void fill_lists_kernel(const int* __restrict__ eidx,
                                                         int* __restrict__ woff_src,
                                                         int* __restrict__ woff_dst,
                                                         int* __restrict__ list_src,
                                                         int* __restrict__ list_dst,
                                                         int E) {
    int e = blockIdx.x * blockDim.x + threadIdx.x;
    if (e >= E) return;
    int s = eidx[e], d = eidx[E + e];
    list_src[atomicAdd(&woff_src[s], 1)] = e;
    list_dst[atomicAdd(&woff_dst[d], 1)] = e;
}

// ============================ main row kernel ==============================
// one workgroup per output row (k, n1, r). LDS row buffer <= 5200 floats.
template <int CPLX>
__global__ __launch_bounds__(256) void row_kernel(const int*   __restrict__ eidx,
                                                  const float* __restrict__ phases,
                                                  const float* __restrict__ hop_pre,
                                                  const float* __restrict__ hopT_pre,
                                                  const float* __restrict__ onsite,
                                                  const int*   __restrict__ off_src,
                                                  const int*   __restrict__ off_dst,
                                                  const int*   __restrict__ list_src,
                                                  const int*   __restrict__ list_dst,
                                                  float* __restrict__ out,
                                                  int N, int E, int K) {
    const int DIMi = N * 13;
    const int wg = blockIdx.x;
    const int k  = wg / DIMi;
    const int a  = wg - k * DIMi;
    const int n1 = a / 13, r = a - n1 * 13;
    const int tid = threadIdx.x;

    __shared__ float buf[5200];
    const int rowf = CPLX ? DIMi * 2 : DIMi;      // floats in this row
    const int row4 = rowf >> 2;                   // rowf is a multiple of 4

    // zero the row buffer (vectorized)
    float4* b4 = (float4*)buf;
    const float4 z = {0.f, 0.f, 0.f, 0.f};
    for (int t = tid; t < row4; t += 256) b4[t] = z;
    __syncthreads();

    // diagonal segment (plain stores; separated from atomics by the barrier)
    if (tid < 13) {
        float v = onsite[n1 * 169 + r * 13 + tid];
        int col = n1 * 13 + tid;
        if (CPLX) buf[col * 2] = v; else buf[col] = v;
    }
    __syncthreads();

    // incident edges: src-direction (this node's rows of H0) and
    // dst-direction (mirror rows: conj of transposed block)
    const int s0 = off_src[n1], ns = off_src[n1 + 1] - s0;
    const int d0 = off_dst[n1], nd = off_dst[n1 + 1] - d0;
    const int total = (ns + nd) * 13;

    for (int it = tid; it < total; it += 256) {
        int ei = it / 13, c = it - ei * 13;
        float pr, pi; int col;
        if (ei < ns) {
            int e  = list_src[s0 + ei];
            int dn = eidx[E + e];
            float h = hop_pre[(long)e * 169 + r * 13 + c];
            const float* ph = &phases[((long)e * K + k) * 2];
            pr = h * ph[0];            // h * cos
            pi = -h * ph[1];           // -h * sin   (e^{-i th})
            col = dn * 13 + c;
        } else {
            int e  = list_dst[d0 + (ei - ns)];
            int sn = eidx[e];
            float h = hopT_pre[(long)e * 169 + r * 13 + c];
            const float* ph = &phases[((long)e * K + k) * 2];
            pr = h * ph[0];            // h * cos
            pi = h * ph[1];            // +h * sin   (conj mirror)
            col = sn * 13 + c;
        }
        if (CPLX) {
            atomicAdd(&buf[col * 2],     pr);
            atomicAdd(&buf[col * 2 + 1], pi);
        } else {
            atomicAdd(&buf[col], pr);
        }
    }
    __syncthreads();

    // stream the finished row to global: coalesced float4, written once
    long base = ((long)k * DIMi + a) * (long)rowf;
    float4* o4 = (float4*)(out + base);
    for (int t = tid; t < row4; t += 256) o4[t] = b4[t];
}

// ====================== fallback path (round-3, verified) ==================

__global__ __launch_bounds__(256) void zero_kernel(float* __restrict__ out, long n) {
    long n4 = n >> 2;
    float4* out4 = (float4*)out;
    long i = (long)blockIdx.x * blockDim.x + threadIdx.x;
    long stride = (long)gridDim.x * blockDim.x;
    const float4 z = {0.f, 0.f, 0.f, 0.f};
    for (long t = i; t < n4; t += stride) out4[t] = z;
    if (i == 0) for (long j = n4 << 2; j < n; ++j) out[j] = 0.f;
}

template <int CPLX>
__global__ __launch_bounds__(256) void diag_kernel(const float* __restrict__ nf,
                                                   float* __restrict__ out,
                                                   int N, int total, long out_lim) {
    int t = blockIdx.x * blockDim.x + threadIdx.x;
    if (t >= total) return;
    int per_k = N * 169;
    int k = t / per_k, rem = t - k * per_k;
    int n = rem / 169, idx = rem - n * 169;
    int r = idx / 13, c = idx - r * 13;
    float v = 0.5f * (nf[n * 107 + nmap(r, c)] + nf[n * 107 + nmap(c, r)]);
    long DIM = (long)N * 13;
    long off = ((long)k * DIM + (long)n * 13 + r) * DIM + (long)n * 13 + c;
    if (CPLX) off *= 2;
    if (off >= 0 && off < out_lim) out[off] = v;
}

template <int CPLX>
__global__ __launch_bounds__(256) void edge_kernel(const float* __restrict__ ef,
                                                   const float* __restrict__ kp,
                                                   const float* __restrict__ ecs,
                                                   const int*   __restrict__ eidx,
                                                   float* __restrict__ out,
                                                   int N, int E, int K, long out_lim) {
    const int e = blockIdx.x;
    __shared__ float hop_sh[169];
    __shared__ float cos_sh[32];
    __shared__ float sin_sh[32];
    const int tid = threadIdx.x;
    const int r = tid / 13, c = tid - r * 13;

    if (tid < 169) hop_sh[tid] = ef[(long)e * 169 + pmap(r, c)];
    if (tid < K && tid < 32) {
        float sx = ecs[e * 3 + 0], sy = ecs[e * 3 + 1], sz = ecs[e * 3 + 2];
        float dot = kp[tid * 3 + 0] * sx + kp[tid * 3 + 1] * sy + kp[tid * 3 + 2] * sz;
        float th = 6.28318530717958647692f * dot;
        float s, co;
        sincosf(th, &s, &co);
        cos_sh[tid] = co;
        sin_sh[tid] = s;
    }
    __syncthreads();
    if (tid >= 169) return;

    const int src = eidx[e];
    const int dst = eidx[E + e];
    const long DIM = (long)N * 13;
    const long SL  = DIM * DIM;
    const float h  = hop_sh[tid];
    const float ht = hop_sh[c * 13 + r];
    const long base1 = ((long)src * 13 + r) * DIM + (long)dst * 13 + c;
    const long base2 = ((long)dst * 13 + r) * DIM + (long)src * 13 + c;

    for (int k = 0; k < K; ++k) {
        float co = cos_sh[k & 31];
        float si = sin_sh[k & 31];
        if (CPLX) {
            long o1 = ((long)k * SL + base1) * 2;
            long o2 = ((long)k * SL + base2) * 2;
            if (o1 >= 0 && o1 + 1 < out_lim) {
                atomicAdd(out + o1,      h * co);
                atomicAdd(out + o1 + 1, -h * si);
            }
            if (o2 >= 0 && o2 + 1 < out_lim) {
                atomicAdd(out + o2,     ht * co);
                atomicAdd(out + o2 + 1, ht * si);
            }
        } else {
            long o1 = (long)k * SL + base1;
            long o2 = (long)k * SL + base2;
            if (o1 >= 0 && o1 < out_lim) atomicAdd(out + o1, h * co);
            if (o2 >= 0 && o2 < out_lim) atomicAdd(out + o2, ht * co);
        }
    }
}

// ================================ launch ===================================

extern "C" void kernel_launch(void* const* d_in, const int* in_sizes, int n_in,
                              void* d_out, int out_size, void* d_ws, size_t ws_size,
                              hipStream_t stream) {
    const float* ef   = (const float*)d_in[0];   // edge_features   (E, 169)
    const float* nf   = (const float*)d_in[1];   // node_features   (N, 107)
    const float* kp   = (const float*)d_in[2];   // kpoints         (K, 3)
    const float* ecs  = (const float*)d_in[3];   // edge_cell_shift (E, 3)
    const int*   eidx = (const int*)d_in[4];     // edge_index      (2, E)

    const int E = in_sizes[0] / 169;
    const int N = in_sizes[1] / 107;
    const int K = in_sizes[2] / 3;

    float* out = (float*)d_out;
    const long DIM  = (long)N * 13;
    const long SL   = DIM * DIM;
    const long full = (long)K * SL * 2;
    const int  cplx = ((long)out_size >= full) ? 1 : 0;
    const long out_lim = (long)out_size;

    // ---- ws layout (all sections 16B-aligned) ----
    const long nPh   = (long)E * K * 2;          // phases
    const long nHop  = (long)E * 169;            // hop_pre
    const long nOn   = (long)N * 169;            // onsite
    long f_off = 0;
    const long o_phases = f_off; f_off += nPh;
    const long o_hop    = f_off; f_off += nHop;
    const long o_hopT   = f_off; f_off += nHop;
    const long o_onsite = f_off; f_off += nOn;
    f_off = (f_off + 3) & ~3L;
    const long i_base   = f_off;                 // ints start here (float slots)
    long i_off = 0;
    const long o_offs   = i_off; i_off += N + 1; // off_src
    const long o_offd   = i_off; i_off += N + 1; // off_dst
    const long o_woffs  = i_off; i_off += N;
    const long o_woffd  = i_off; i_off += N;
    const long o_cnts   = i_off; i_off += N;
    const long o_cntd   = i_off; i_off += N;
    const long o_lists  = i_off; i_off += E;
    const long o_listd  = i_off; i_off += E;
    const long req_bytes = (i_base + i_off) * 4;

    const int rowf = (int)DIM * (cplx ? 2 : 1);
    const bool fast_ok = (ws_size >= (size_t)req_bytes) && (N <= 256) &&
                         (K <= 256) && (rowf <= 5200);

    if (fast_ok) {
        float* wf = (float*)d_ws;
        int*   wi = (int*)d_ws + i_base;
        float* phases   = wf + o_phases;
        float* hop_pre  = wf + o_hop;
        float* hopT_pre = wf + o_hopT;
        float* onsite   = wf + o_onsite;
        int* off_src  = wi + o_offs;
        int* off_dst  = wi + o_offd;
        int* woff_src = wi + o_woffs;
        int* woff_dst = wi + o_woffd;
        int* cnt_src  = wi + o_cnts;
        int* cnt_dst  = wi + o_cntd;
        int* list_src = wi + o_lists;
        int* list_dst = wi + o_listd;

        // 1) zero degree counters
        zero_ints_kernel<<<(2 * N + 255) / 256, 256, 0, stream>>>(cnt_src, 2 * N);
        // 2) per-edge preprocessing + degree counting
        edge_pre_kernel<<<E, 256, 0, stream>>>(ef, kp, ecs, eidx, phases,
                                               hop_pre, hopT_pre, cnt_src, cnt_dst, E, K);
        // 3) symmetrized onsite blocks
        int tot_on = N * 169;
        onsite_pre_kernel<<<(tot_on + 255) / 256, 256, 0, stream>>>(nf, onsite, tot_on);
        // 4) CSR offsets
        scan_kernel<<<1, 256, 0, stream>>>(cnt_src, cnt_dst, off_src, off_dst,
                                           woff_src, woff_dst, N);
        // 5) CSR lists
        fill_lists_kernel<<<(E + 255) / 256, 256, 0, stream>>>(eidx, woff_src, woff_dst,
                                                               list_src, list_dst, E);
        // 6) main: one workgroup per output row, single write pass
        int grid = K * (int)DIM;
        if (cplx)
            row_kernel<1><<<grid, 256, 0, stream>>>(eidx, phases, hop_pre, hopT_pre,
                                                    onsite, off_src, off_dst,
                                                    list_src, list_dst, out, N, E, K);
        else
            row_kernel<0><<<grid, 256, 0, stream>>>(eidx, phases, hop_pre, hopT_pre,
                                                    onsite, off_src, off_dst,
                                                    list_src, list_dst, out, N, E, K);
    } else {
        // verified round-3 fallback
        zero_kernel<<<2048, 256, 0, stream>>>(out, out_lim);
        int total_diag = K * N * 169;
        int blocks_diag = (total_diag + 255) / 256;
        if (cplx) {
            diag_kernel<1><<<blocks_diag, 256, 0, stream>>>(nf, out, N, total_diag, out_lim);
            edge_kernel<1><<<E, 256, 0, stream>>>(ef, kp, ecs, eidx, out, N, E, K, out_lim);
        } else {
            diag_kernel<0><<<blocks_diag, 256, 0, stream>>>(nf, out, N, total_diag, out_lim);
            edge_kernel<0><<<E, 256, 0, stream>>>(ef, kp, ecs, eidx, out, N, E, K, out_lim);
        }
    }
}